// Round 3
// baseline (20416.966 us; speedup 1.0000x reference)
//
#include <hip/hip_runtime.h>
#include <hip/hip_fp16.h>

#define BS 256
#define T 256
#define STEPS 255
#define WV 100
#define INP 64
#define H 256
#define G4 1024
#define VOCAB 600

typedef float f32x2 __attribute__((ext_vector_type(2)));

// ---------------- sort: stable descending by length (jax argsort(-len)) ----
__global__ void k_sort(const int* __restrict__ lens, int* __restrict__ sidx,
                       int* __restrict__ dlen, float* __restrict__ out_dec,
                       float* __restrict__ out_sidx) {
    __shared__ int L[BS];
    int i = threadIdx.x;
    L[i] = lens[i];
    __syncthreads();
    int li = L[i];
    int r = 0;
    for (int j = 0; j < BS; ++j) {
        int lj = L[j];
        r += (lj > li) || (lj == li && j < i);
    }
    sidx[r] = i;
    dlen[r] = li - 1;
    out_sidx[r] = (float)i;
    out_dec[r]  = (float)(li - 1);
}

// ---------------- gather sorted captions to output ------------------------
__global__ void k_gather(const float* __restrict__ cin, const int* __restrict__ sidx,
                         float* __restrict__ cout) {
    int b = blockIdx.x;
    int src = sidx[b];
    const float4* in  = (const float4*)(cin + (size_t)src * T * WV);
    float4* out       = (float4*)(cout + (size_t)b * T * WV);
    for (int i = threadIdx.x; i < T * WV / 4; i += 256) out[i] = in[i];
}

// ---------------- W_comb = w_ih @ W_emb^T  [1024 x 100] -------------------
__global__ void k_wcomb(const float* __restrict__ w_ih, const float* __restrict__ W_emb,
                        float* __restrict__ Wc) {
    int idx = blockIdx.x * 256 + threadIdx.x;   // 102400 threads
    int r = idx / WV, cc = idx % WV;
    float acc = 0.f;
    for (int k = 0; k < INP; ++k) acc += w_ih[r * INP + k] * W_emb[k * WV + cc];
    Wc[idx] = acc;
}

// ---------------- b_comb = b_ih + b_hh + w_ih @ b_emb ---------------------
__global__ void k_bcomb(const float* __restrict__ w_ih, const float* __restrict__ b_ih,
                        const float* __restrict__ b_hh, const float* __restrict__ b_emb,
                        float* __restrict__ bc) {
    int r = blockIdx.x * 256 + threadIdx.x;     // 1024 threads
    float acc = b_ih[r] + b_hh[r];
    for (int k = 0; k < INP; ++k) acc += w_ih[r * INP + k] * b_emb[k];
    bc[r] = acc;
}

// ---------------- quantize w_hh -> fp8 e4m3, per-row scale ----------------
// wq[kk*1024 + r] = 4 packed fp8 of row r, k = 4kk..4kk+3, scaled by 448/rowmax
__global__ void k_packw8(const float* __restrict__ w_hh, unsigned int* __restrict__ wq,
                         float* __restrict__ wscale) {
    int r = blockIdx.x * 256 + threadIdx.x;   // 1024 rows
    const float* row = w_hh + (size_t)r * H;
    float m = 0.f;
    for (int k = 0; k < H; ++k) m = fmaxf(m, fabsf(row[k]));
    float s, inv;
    if (m > 0.f) { s = m / 448.f; inv = 448.f / m; } else { s = 1.f; inv = 0.f; }
    wscale[r] = s;
    for (int kk = 0; kk < 64; ++kk) {
        int v = __builtin_amdgcn_cvt_pk_fp8_f32(row[4 * kk] * inv, row[4 * kk + 1] * inv, 0, false);
        v = __builtin_amdgcn_cvt_pk_fp8_f32(row[4 * kk + 2] * inv, row[4 * kk + 3] * inv, v, true);
        wq[kk * 1024 + r] = (unsigned int)v;
    }
}

// ---------------- h0 = enc@W_h^T + b_h ; c0 = enc@W_c^T + b_c -------------
__global__ void k_inithc(const float* __restrict__ enc, const int* __restrict__ sidx,
                         const float* __restrict__ W_h, const float* __restrict__ b_h,
                         const float* __restrict__ W_c, const float* __restrict__ b_c,
                         float* __restrict__ h_st, float* __restrict__ c_st) {
    int b = blockIdx.x, j = threadIdx.x;
    __shared__ __align__(16) float e[INP];
    int src = sidx[b];
    if (j < INP) e[j] = enc[src * INP + j];
    __syncthreads();
    const float4* e4  = (const float4*)e;
    const float4* wh4 = (const float4*)(W_h + (size_t)j * INP);
    const float4* wc4 = (const float4*)(W_c + (size_t)j * INP);
    float ah = b_h[j], ac = b_c[j];
    #pragma unroll
    for (int k4 = 0; k4 < INP / 4; ++k4) {
        float4 ev = e4[k4];
        float4 wh = wh4[k4];
        float4 wc = wc4[k4];
        ah += ev.x * wh.x + ev.y * wh.y + ev.z * wh.z + ev.w * wh.w;
        ac += ev.x * wc.x + ev.y * wc.y + ev.z * wc.z + ev.w * wc.w;
    }
    h_st[b * H + j] = ah;
    c_st[b * H + j] = ac;
}

// ---------------- xg[b,ct,:] = caps_sorted[b,t,:] @ W_comb^T + b_comb -----
__global__ void k_xg(const float* __restrict__ caps, const float* __restrict__ Wc,
                     const float* __restrict__ bc, const int* __restrict__ dlen,
                     float* __restrict__ xg, int t0, int Cc) {
    int b = blockIdx.y;
    int ct0 = blockIdx.x * 16;
    if (t0 + ct0 >= dlen[b]) return;   // rows never consumed by the LSTM
    __shared__ __align__(16) float4 cs4[16][WV / 4];   // 16 timesteps x 100
    float* cs = (float*)cs4;
    for (int i = threadIdx.x; i < 16 * WV; i += 256) {
        int rr = i / WV, k = i % WV;
        int t = t0 + ct0 + rr;
        cs[rr * WV + k] = (t < T && ct0 + rr < Cc) ? caps[((size_t)b * T + t) * WV + k] : 0.f;
    }
    __syncthreads();
    int nrow = Cc - ct0; if (nrow > 16) nrow = 16;
    for (int rq = 0; rq < 4; ++rq) {
        int r = threadIdx.x + rq * 256;
        float acc[16];
        float bv = bc[r];
        #pragma unroll
        for (int rr = 0; rr < 16; ++rr) acc[rr] = bv;
        const float4* wr = (const float4*)(Wc + (size_t)r * WV);
        for (int k4 = 0; k4 < WV / 4; ++k4) {
            float4 w = wr[k4];
            #pragma unroll
            for (int rr = 0; rr < 16; ++rr) {
                float4 av = cs4[rr][k4];
                acc[rr] += av.x * w.x + av.y * w.y + av.z * w.z + av.w * w.w;
            }
        }
        for (int rr = 0; rr < nrow; ++rr)
            xg[((size_t)b * Cc + ct0 + rr) * G4 + r] = acc[rr];
    }
}

// ---------------- recurrent LSTM core: one block per batch row ------------
// 512 threads (8 waves, 2 waves/SIMD -> 256-VGPR cap, 1 block/CU).
// Thread t owns gate rows {t, t+512} as fp8-e4m3 packed in 128 VGPRs
// (register-resident; zero per-step weight memory traffic). Per-row scale
// wscale restores magnitude. h broadcast from LDS (same-address
// ds_read_b128 = conflict-free). Gate rows: i=[0,256) f=[256,512)
// g=[512,768) o=[768,1024); so t<256 computes (i,g), t>=256 computes (f,o).
__global__ __launch_bounds__(512, 2) void k_lstm(const unsigned int* __restrict__ wq,
        const float* __restrict__ wscale, const float* __restrict__ xg,
        const int* __restrict__ dlen, float* __restrict__ h_st,
        float* __restrict__ c_st, __half* __restrict__ hck, int t0, int Cc) {
    int b = blockIdx.x, tid = threadIdx.x;
    int steps_b = dlen[b];
    if (t0 >= steps_b) return;          // block-uniform: safe before syncs

    // one-time: my two gate rows into registers (64+64 packed-fp8 dwords)
    unsigned int wA[64], wB[64];
    #pragma unroll
    for (int kk = 0; kk < 64; ++kk) {
        wA[kk] = wq[kk * 1024 + tid];
        wB[kk] = wq[kk * 1024 + tid + 512];
    }
    float sA = wscale[tid], sB = wscale[tid + 512];

    __shared__ __align__(16) float hsh[H];
    __shared__ float sfb[H], sob[H];
    float c = 0.f;
    if (tid < H) { hsh[tid] = h_st[b * H + tid]; c = c_st[b * H + tid]; }
    __syncthreads();

    int tend = t0 + Cc; if (tend > steps_b) tend = steps_b;
    int nsteps = tend - t0;
    const float* xgp = xg + (size_t)b * Cc * G4;
    float xA = xgp[tid], xB = xgp[tid + 512];

    for (int st = 0; st < nsteps; ++st) {
        f32x2 a0 = {0.f, 0.f}, a1 = {0.f, 0.f};
        f32x2 c0 = {0.f, 0.f}, c1 = {0.f, 0.f};
        const float4* h4 = (const float4*)hsh;
        #pragma unroll
        for (int kk = 0; kk < 64; kk += 2) {
            float4 h0 = h4[kk], h1 = h4[kk + 1];
            f32x2 h0l = {h0.x, h0.y}, h0h = {h0.z, h0.w};
            f32x2 h1l = {h1.x, h1.y}, h1h = {h1.z, h1.w};
            unsigned int wa0 = wA[kk], wa1 = wA[kk + 1];
            unsigned int wb0 = wB[kk], wb1 = wB[kk + 1];
            a0 += __builtin_amdgcn_cvt_pk_f32_fp8(wa0, false) * h0l;
            a0 += __builtin_amdgcn_cvt_pk_f32_fp8(wa0, true)  * h0h;
            a1 += __builtin_amdgcn_cvt_pk_f32_fp8(wa1, false) * h1l;
            a1 += __builtin_amdgcn_cvt_pk_f32_fp8(wa1, true)  * h1h;
            c0 += __builtin_amdgcn_cvt_pk_f32_fp8(wb0, false) * h0l;
            c0 += __builtin_amdgcn_cvt_pk_f32_fp8(wb0, true)  * h0h;
            c1 += __builtin_amdgcn_cvt_pk_f32_fp8(wb1, false) * h1l;
            c1 += __builtin_amdgcn_cvt_pk_f32_fp8(wb1, true)  * h1h;
        }
        f32x2 sa = a0 + a1, sb = c0 + c1;
        float gA = xA + sA * (sa.x + sa.y);
        float gB = xB + sB * (sb.x + sb.y);
        if (st + 1 < nsteps) {
            xA = xgp[(size_t)(st + 1) * G4 + tid];
            xB = xgp[(size_t)(st + 1) * G4 + tid + 512];
        }
        if (tid >= H) {                       // f and o gates
            sfb[tid - H] = 1.f / (1.f + __expf(-gA));
            sob[tid - H] = 1.f / (1.f + __expf(-gB));
        }
        __syncthreads();
        if (tid < H) {                        // i and g gates + state update
            float iv = 1.f / (1.f + __expf(-gA));
            float gv = tanhf(gB);
            c = sfb[tid] * c + iv * gv;
            float nh = sob[tid] * tanhf(c);
            hsh[tid] = nh;
            hck[((size_t)b * Cc + st) * H + tid] = __float2half(nh);
        }
        __syncthreads();
    }
    if (tid < H) { h_st[b * H + tid] = hsh[tid]; c_st[b * H + tid] = c; }
}

// ---------------- logits = h @ W_out^T + b_out, masked with -1 ------------
__global__ void k_logits(const __half* __restrict__ hck, const float* __restrict__ Wo,
                         const float* __restrict__ bo, const int* __restrict__ dlen,
                         float* __restrict__ pred, int t0, int Cc) {
    int b = blockIdx.y;
    int ct0 = blockIdx.x * 16;
    if (ct0 >= Cc) return;
    int steps_b = dlen[b];
    int nrow = Cc - ct0; if (nrow > 16) nrow = 16;
    if (t0 + ct0 >= steps_b) {   // whole tile inactive: write -1
        for (int rr = 0; rr < nrow; ++rr) {
            int t = t0 + ct0 + rr;
            if (t >= STEPS) break;
            float* pr = pred + ((size_t)b * STEPS + t) * VOCAB;
            for (int cidx = threadIdx.x; cidx < VOCAB; cidx += 256) pr[cidx] = -1.f;
        }
        return;
    }
    __shared__ __align__(16) float4 a4[16][H / 4];
    float* a = (float*)a4;
    for (int i = threadIdx.x; i < 16 * H; i += 256) {
        int rr = i >> 8, k = i & 255;
        float v = (rr < nrow) ? __half2float(hck[((size_t)b * Cc + ct0 + rr) * H + k]) : 0.f;
        a[rr * H + k] = v;
    }
    __syncthreads();
    for (int cidx = threadIdx.x; cidx < VOCAB; cidx += 256) {
        const float4* wr = (const float4*)(Wo + (size_t)cidx * H);
        float acc[16];
        float bv = bo[cidx];
        #pragma unroll
        for (int rr = 0; rr < 16; ++rr) acc[rr] = bv;
        for (int k4 = 0; k4 < H / 4; ++k4) {
            float4 w = wr[k4];
            #pragma unroll
            for (int rr = 0; rr < 16; ++rr) {
                float4 av = a4[rr][k4];
                acc[rr] += av.x * w.x + av.y * w.y + av.z * w.z + av.w * w.w;
            }
        }
        for (int rr = 0; rr < nrow; ++rr) {
            int t = t0 + ct0 + rr;
            if (t >= STEPS) break;
            pred[((size_t)b * STEPS + t) * VOCAB + cidx] = (t < steps_b) ? acc[rr] : -1.f;
        }
    }
}

extern "C" void kernel_launch(void* const* d_in, const int* in_sizes, int n_in,
                              void* d_out, int out_size, void* d_ws, size_t ws_size,
                              hipStream_t stream) {
    const float* enc   = (const float*)d_in[0];
    const float* caps  = (const float*)d_in[1];
    const float* w_ih  = (const float*)d_in[2];
    const float* w_hh  = (const float*)d_in[3];
    const float* b_ih  = (const float*)d_in[4];
    const float* b_hh  = (const float*)d_in[5];
    const float* W_out = (const float*)d_in[6];
    const float* b_out = (const float*)d_in[7];
    const float* W_emb = (const float*)d_in[8];
    const float* b_emb = (const float*)d_in[9];
    const float* W_h   = (const float*)d_in[10];
    const float* b_h   = (const float*)d_in[11];
    const float* W_c   = (const float*)d_in[12];
    const float* b_c   = (const float*)d_in[13];
    const int*   lens  = (const int*)d_in[14];

    float* out_pred = (float*)d_out;
    float* out_caps = out_pred + (size_t)BS * STEPS * VOCAB;
    float* out_dec  = out_caps + (size_t)BS * T * WV;
    float* out_sidx = out_dec + BS;

    char* w = (char*)d_ws;
    size_t off = 0;
    auto take = [&](size_t bytes) -> char* {
        char* p = w + off;
        off += (bytes + 255) & ~(size_t)255;
        return p;
    };
    int*          sidx   = (int*)take(BS * 4);
    int*          dlen   = (int*)take(BS * 4);
    float*        Wc     = (float*)take((size_t)G4 * WV * 4);
    float*        bc     = (float*)take(G4 * 4);
    float*        h_st   = (float*)take((size_t)BS * H * 4);
    float*        c_st   = (float*)take((size_t)BS * H * 4);
    unsigned int* wq     = (unsigned int*)take((size_t)64 * G4 * 4);
    float*        wscale = (float*)take(G4 * 4);

    size_t rem = (ws_size > off) ? (ws_size - off) : 0;
    size_t per_step = (size_t)BS * G4 * 4 + (size_t)BS * H * 2 + 1024;
    int C = (int)(rem / per_step);
    if (C < 1) C = 1;
    if (C > STEPS) C = STEPS;
    float*  xg  = (float*)take((size_t)BS * C * G4 * 4);
    __half* hck = (__half*)take((size_t)BS * C * H * 2);

    k_sort<<<1, 256, 0, stream>>>(lens, sidx, dlen, out_dec, out_sidx);
    k_gather<<<BS, 256, 0, stream>>>(caps, sidx, out_caps);
    k_wcomb<<<G4 * WV / 256, 256, 0, stream>>>(w_ih, W_emb, Wc);
    k_bcomb<<<G4 / 256, 256, 0, stream>>>(w_ih, b_ih, b_hh, b_emb, bc);
    k_packw8<<<4, 256, 0, stream>>>(w_hh, wq, wscale);
    k_inithc<<<BS, 256, 0, stream>>>(enc, sidx, W_h, b_h, W_c, b_c, h_st, c_st);

    for (int t0 = 0; t0 < STEPS; t0 += C) {
        int Cc = STEPS - t0; if (Cc > C) Cc = C;
        dim3 g((Cc + 15) / 16, BS);
        k_xg<<<g, 256, 0, stream>>>(out_caps, Wc, bc, dlen, xg, t0, Cc);
        k_lstm<<<BS, 512, 0, stream>>>(wq, wscale, xg, dlen, h_st, c_st, hck, t0, Cc);
        k_logits<<<g, 256, 0, stream>>>(hck, W_out, b_out, dlen, out_pred, t0, Cc);
    }
}

// Round 4
// 17461.060 us; speedup vs baseline: 1.1693x; 1.1693x over previous
//
#include <hip/hip_runtime.h>
#include <hip/hip_fp16.h>

#define BS 256
#define T 256
#define STEPS 255
#define WV 100
#define INP 64
#define H 256
#define G4 1024
#define VOCAB 600

// w_hh K-split: first KL columns LDS-resident (static 48 KB), rest streamed from L2
#define JL 3                 // 16-elem k-groups in LDS   (k = 0..47)
#define JS 13                // 16-elem k-groups streamed (k = 48..255)

typedef float f32x2 __attribute__((ext_vector_type(2)));
typedef unsigned int uint;

// ---------------- sort: stable descending by length (jax argsort(-len)) ----
__global__ void k_sort(const int* __restrict__ lens, int* __restrict__ sidx,
                       int* __restrict__ dlen, float* __restrict__ out_dec,
                       float* __restrict__ out_sidx) {
    __shared__ int L[BS];
    int i = threadIdx.x;
    L[i] = lens[i];
    __syncthreads();
    int li = L[i];
    int r = 0;
    for (int j = 0; j < BS; ++j) {
        int lj = L[j];
        r += (lj > li) || (lj == li && j < i);
    }
    sidx[r] = i;
    dlen[r] = li - 1;
    out_sidx[r] = (float)i;
    out_dec[r]  = (float)(li - 1);
}

// ---------------- gather sorted captions to output ------------------------
__global__ void k_gather(const float* __restrict__ cin, const int* __restrict__ sidx,
                         float* __restrict__ cout) {
    int b = blockIdx.x;
    int src = sidx[b];
    const float4* in  = (const float4*)(cin + (size_t)src * T * WV);
    float4* out       = (float4*)(cout + (size_t)b * T * WV);
    for (int i = threadIdx.x; i < T * WV / 4; i += 256) out[i] = in[i];
}

// ---------------- W_comb = w_ih @ W_emb^T  [1024 x 100] -------------------
__global__ void k_wcomb(const float* __restrict__ w_ih, const float* __restrict__ W_emb,
                        float* __restrict__ Wc) {
    int idx = blockIdx.x * 256 + threadIdx.x;   // 102400 threads
    int r = idx / WV, cc = idx % WV;
    float acc = 0.f;
    for (int k = 0; k < INP; ++k) acc += w_ih[r * INP + k] * W_emb[k * WV + cc];
    Wc[idx] = acc;
}

// ---------------- b_comb = b_ih + b_hh + w_ih @ b_emb ---------------------
__global__ void k_bcomb(const float* __restrict__ w_ih, const float* __restrict__ b_ih,
                        const float* __restrict__ b_hh, const float* __restrict__ b_emb,
                        float* __restrict__ bc) {
    int r = blockIdx.x * 256 + threadIdx.x;     // 1024 threads
    float acc = b_ih[r] + b_hh[r];
    for (int k = 0; k < INP; ++k) acc += w_ih[r * INP + k] * b_emb[k];
    bc[r] = acc;
}

// ---------------- quantize w_hh -> fp8 e4m3, per-row scale ----------------
// Dword layout for both halves: dw[((j*1024)+row)*4 + d] holds elems
// k = base + j*16 + d*4 .. +3 of `row` (perfectly lane-coalesced: a wave's
// uint4 load at (j*1024+tid) is a contiguous 1 KB segment).
__global__ void k_packw8(const float* __restrict__ w_hh, uint* __restrict__ wq_l,
                         uint* __restrict__ wq_s, float* __restrict__ wscale) {
    int r = blockIdx.x * 256 + threadIdx.x;   // 1024 rows
    const float* row = w_hh + (size_t)r * H;
    float m = 0.f;
    for (int k = 0; k < H; ++k) m = fmaxf(m, fabsf(row[k]));
    float s, inv;
    if (m > 0.f) { s = m / 448.f; inv = 448.f / m; } else { s = 1.f; inv = 0.f; }
    wscale[r] = s;
    for (int kk = 0; kk < 64; ++kk) {         // dword kk = elems 4kk..4kk+3
        int v = __builtin_amdgcn_cvt_pk_fp8_f32(row[4 * kk] * inv, row[4 * kk + 1] * inv, 0, false);
        v = __builtin_amdgcn_cvt_pk_fp8_f32(row[4 * kk + 2] * inv, row[4 * kk + 3] * inv, v, true);
        if (kk < JL * 4) {
            int j = kk >> 2, d = kk & 3;
            wq_l[((j * 1024) + r) * 4 + d] = (uint)v;
        } else {
            int kk2 = kk - JL * 4;
            int j = kk2 >> 2, d = kk2 & 3;
            wq_s[((j * 1024) + r) * 4 + d] = (uint)v;
        }
    }
}

// ---------------- h0 = enc@W_h^T + b_h ; c0 = enc@W_c^T + b_c -------------
__global__ void k_inithc(const float* __restrict__ enc, const int* __restrict__ sidx,
                         const float* __restrict__ W_h, const float* __restrict__ b_h,
                         const float* __restrict__ W_c, const float* __restrict__ b_c,
                         float* __restrict__ h_st, float* __restrict__ c_st) {
    int b = blockIdx.x, j = threadIdx.x;
    __shared__ __align__(16) float e[INP];
    int src = sidx[b];
    if (j < INP) e[j] = enc[src * INP + j];
    __syncthreads();
    const float4* e4  = (const float4*)e;
    const float4* wh4 = (const float4*)(W_h + (size_t)j * INP);
    const float4* wc4 = (const float4*)(W_c + (size_t)j * INP);
    float ah = b_h[j], ac = b_c[j];
    #pragma unroll
    for (int k4 = 0; k4 < INP / 4; ++k4) {
        float4 ev = e4[k4];
        float4 wh = wh4[k4];
        float4 wc = wc4[k4];
        ah += ev.x * wh.x + ev.y * wh.y + ev.z * wh.z + ev.w * wh.w;
        ac += ev.x * wc.x + ev.y * wc.y + ev.z * wc.z + ev.w * wc.w;
    }
    h_st[b * H + j] = ah;
    c_st[b * H + j] = ac;
}

// ---------------- xg[b,ct,:] = caps_sorted[b,t,:] @ W_comb^T + b_comb -----
__global__ void k_xg(const float* __restrict__ caps, const float* __restrict__ Wc,
                     const float* __restrict__ bc, const int* __restrict__ dlen,
                     float* __restrict__ xg, int t0, int Cc) {
    int b = blockIdx.y;
    int ct0 = blockIdx.x * 16;
    if (t0 + ct0 >= dlen[b]) return;   // rows never consumed by the LSTM
    __shared__ __align__(16) float4 cs4[16][WV / 4];   // 16 timesteps x 100
    float* cs = (float*)cs4;
    for (int i = threadIdx.x; i < 16 * WV; i += 256) {
        int rr = i / WV, k = i % WV;
        int t = t0 + ct0 + rr;
        cs[rr * WV + k] = (t < T && ct0 + rr < Cc) ? caps[((size_t)b * T + t) * WV + k] : 0.f;
    }
    __syncthreads();
    int nrow = Cc - ct0; if (nrow > 16) nrow = 16;
    for (int rq = 0; rq < 4; ++rq) {
        int r = threadIdx.x + rq * 256;
        float acc[16];
        float bv = bc[r];
        #pragma unroll
        for (int rr = 0; rr < 16; ++rr) acc[rr] = bv;
        const float4* wr = (const float4*)(Wc + (size_t)r * WV);
        for (int k4 = 0; k4 < WV / 4; ++k4) {
            float4 w = wr[k4];
            #pragma unroll
            for (int rr = 0; rr < 16; ++rr) {
                float4 av = cs4[rr][k4];
                acc[rr] += av.x * w.x + av.y * w.y + av.z * w.z + av.w * w.w;
            }
        }
        for (int rr = 0; rr < nrow; ++rr)
            xg[((size_t)b * Cc + ct0 + rr) * G4 + r] = acc[rr];
    }
}

// 8 fp8 weights (one dword per row A/B) x 4 f32 h values -> accumulate
__device__ __forceinline__ void dot8(uint wa, uint wb, const float4 hv,
                                     f32x2& aA, f32x2& aB) {
    f32x2 hl = {hv.x, hv.y}, hh = {hv.z, hv.w};
    aA += __builtin_amdgcn_cvt_pk_f32_fp8(wa, false) * hl;
    aA += __builtin_amdgcn_cvt_pk_f32_fp8(wa, true)  * hh;
    aB += __builtin_amdgcn_cvt_pk_f32_fp8(wb, false) * hl;
    aB += __builtin_amdgcn_cvt_pk_f32_fp8(wb, true)  * hh;
}

__device__ __forceinline__ void dotg(const uint4 wa, const uint4 wb,
                                     const float4* __restrict__ h4, int d0,
                                     f32x2& aA, f32x2& aB) {
    dot8(wa.x, wb.x, h4[d0 + 0], aA, aB);
    dot8(wa.y, wb.y, h4[d0 + 1], aA, aB);
    dot8(wa.z, wb.z, h4[d0 + 2], aA, aB);
    dot8(wa.w, wb.w, h4[d0 + 3], aA, aB);
}

// ---------------- recurrent LSTM core: one block per batch row ------------
// 512 threads (8 waves). Thread t owns gate rows {t, t+512}: t<256 -> (i,g),
// t>=256 -> (f,o). Weights fp8-e4m3 with per-row scale. k<48 lives in static
// LDS (48 KB, loaded once); k>=48 streamed from L2 each step (208 KB/block,
// lane-coalesced uint4, 1-group register double-buffer). No large per-thread
// arrays -> nothing for the allocator to sink (R2/R3 failure mode).
__global__ __launch_bounds__(512, 2) void k_lstm(const uint4* __restrict__ wq_l,
        const uint4* __restrict__ wq_s, const float* __restrict__ wscale,
        const float* __restrict__ xg, const int* __restrict__ dlen,
        float* __restrict__ h_st, float* __restrict__ c_st,
        __half* __restrict__ hck, int t0, int Cc) {
    __shared__ uint4 wl[JL * 1024];                 // 48 KB weight cache
    __shared__ __align__(16) float hsh[H];
    __shared__ float sfb[H], sob[H];
    int b = blockIdx.x, tid = threadIdx.x;
    int steps_b = dlen[b];
    if (t0 >= steps_b) return;          // block-uniform: safe before syncs

    for (int i = tid; i < JL * 1024; i += 512) wl[i] = wq_l[i];
    float sA = wscale[tid], sB = wscale[tid + 512];
    float c = 0.f;
    if (tid < H) { hsh[tid] = h_st[b * H + tid]; c = c_st[b * H + tid]; }
    __syncthreads();

    int tend = t0 + Cc; if (tend > steps_b) tend = steps_b;
    int nsteps = tend - t0;
    const float* xgp = xg + (size_t)b * Cc * G4;
    float xA = xgp[tid], xB = xgp[tid + 512];

    for (int st = 0; st < nsteps; ++st) {
        const float4* h4 = (const float4*)hsh;
        f32x2 aA = {0.f, 0.f}, aB = {0.f, 0.f};
        // LDS-resident k-groups (k = 0..47)
        #pragma unroll
        for (int j = 0; j < JL; ++j) {
            uint4 wa = wl[j * 1024 + tid];
            uint4 wb = wl[j * 1024 + tid + 512];
            dotg(wa, wb, h4, j * 4, aA, aB);
        }
        // streamed k-groups (k = 48..255), prefetch one group ahead
        uint4 pa = wq_s[tid], pb = wq_s[tid + 512];
        #pragma unroll
        for (int j = 0; j < JS; ++j) {
            uint4 wa = pa, wb = pb;
            if (j + 1 < JS) {
                pa = wq_s[(j + 1) * 1024 + tid];
                pb = wq_s[(j + 1) * 1024 + tid + 512];
            }
            dotg(wa, wb, h4, (JL + j) * 4, aA, aB);
        }
        float gA = xA + sA * (aA.x + aA.y);
        float gB = xB + sB * (aB.x + aB.y);
        if (st + 1 < nsteps) {
            xA = xgp[(size_t)(st + 1) * G4 + tid];
            xB = xgp[(size_t)(st + 1) * G4 + tid + 512];
        }
        if (tid >= H) {                       // f and o gates
            sfb[tid - H] = 1.f / (1.f + __expf(-gA));
            sob[tid - H] = 1.f / (1.f + __expf(-gB));
        }
        __syncthreads();
        if (tid < H) {                        // i and g gates + state update
            float iv = 1.f / (1.f + __expf(-gA));
            float gv = tanhf(gB);
            c = sfb[tid] * c + iv * gv;
            float nh = sob[tid] * tanhf(c);
            hsh[tid] = nh;
            hck[((size_t)b * Cc + st) * H + tid] = __float2half(nh);
        }
        __syncthreads();
    }
    if (tid < H) { h_st[b * H + tid] = hsh[tid]; c_st[b * H + tid] = c; }
}

// ---------------- logits = h @ W_out^T + b_out, masked with -1 ------------
__global__ void k_logits(const __half* __restrict__ hck, const float* __restrict__ Wo,
                         const float* __restrict__ bo, const int* __restrict__ dlen,
                         float* __restrict__ pred, int t0, int Cc) {
    int b = blockIdx.y;
    int ct0 = blockIdx.x * 16;
    if (ct0 >= Cc) return;
    int steps_b = dlen[b];
    int nrow = Cc - ct0; if (nrow > 16) nrow = 16;
    if (t0 + ct0 >= steps_b) {   // whole tile inactive: write -1
        for (int rr = 0; rr < nrow; ++rr) {
            int t = t0 + ct0 + rr;
            if (t >= STEPS) break;
            float* pr = pred + ((size_t)b * STEPS + t) * VOCAB;
            for (int cidx = threadIdx.x; cidx < VOCAB; cidx += 256) pr[cidx] = -1.f;
        }
        return;
    }
    __shared__ __align__(16) float4 a4[16][H / 4];
    float* a = (float*)a4;
    for (int i = threadIdx.x; i < 16 * H; i += 256) {
        int rr = i >> 8, k = i & 255;
        float v = (rr < nrow) ? __half2float(hck[((size_t)b * Cc + ct0 + rr) * H + k]) : 0.f;
        a[rr * H + k] = v;
    }
    __syncthreads();
    for (int cidx = threadIdx.x; cidx < VOCAB; cidx += 256) {
        const float4* wr = (const float4*)(Wo + (size_t)cidx * H);
        float acc[16];
        float bv = bo[cidx];
        #pragma unroll
        for (int rr = 0; rr < 16; ++rr) acc[rr] = bv;
        for (int k4 = 0; k4 < H / 4; ++k4) {
            float4 w = wr[k4];
            #pragma unroll
            for (int rr = 0; rr < 16; ++rr) {
                float4 av = a4[rr][k4];
                acc[rr] += av.x * w.x + av.y * w.y + av.z * w.z + av.w * w.w;
            }
        }
        for (int rr = 0; rr < nrow; ++rr) {
            int t = t0 + ct0 + rr;
            if (t >= STEPS) break;
            pred[((size_t)b * STEPS + t) * VOCAB + cidx] = (t < steps_b) ? acc[rr] : -1.f;
        }
    }
}

extern "C" void kernel_launch(void* const* d_in, const int* in_sizes, int n_in,
                              void* d_out, int out_size, void* d_ws, size_t ws_size,
                              hipStream_t stream) {
    const float* enc   = (const float*)d_in[0];
    const float* caps  = (const float*)d_in[1];
    const float* w_ih  = (const float*)d_in[2];
    const float* w_hh  = (const float*)d_in[3];
    const float* b_ih  = (const float*)d_in[4];
    const float* b_hh  = (const float*)d_in[5];
    const float* W_out = (const float*)d_in[6];
    const float* b_out = (const float*)d_in[7];
    const float* W_emb = (const float*)d_in[8];
    const float* b_emb = (const float*)d_in[9];
    const float* W_h   = (const float*)d_in[10];
    const float* b_h   = (const float*)d_in[11];
    const float* W_c   = (const float*)d_in[12];
    const float* b_c   = (const float*)d_in[13];
    const int*   lens  = (const int*)d_in[14];

    float* out_pred = (float*)d_out;
    float* out_caps = out_pred + (size_t)BS * STEPS * VOCAB;
    float* out_dec  = out_caps + (size_t)BS * T * WV;
    float* out_sidx = out_dec + BS;

    char* w = (char*)d_ws;
    size_t off = 0;
    auto take = [&](size_t bytes) -> char* {
        char* p = w + off;
        off += (bytes + 255) & ~(size_t)255;
        return p;
    };
    int*   sidx   = (int*)take(BS * 4);
    int*   dlen   = (int*)take(BS * 4);
    float* Wc     = (float*)take((size_t)G4 * WV * 4);
    float* bc     = (float*)take(G4 * 4);
    float* h_st   = (float*)take((size_t)BS * H * 4);
    float* c_st   = (float*)take((size_t)BS * H * 4);
    uint*  wq_l   = (uint*)take((size_t)JL * 1024 * 16);   // 48 KB, LDS layout
    uint*  wq_s   = (uint*)take((size_t)JS * 1024 * 16);   // 208 KB, stream layout
    float* wscale = (float*)take(G4 * 4);

    size_t rem = (ws_size > off) ? (ws_size - off) : 0;
    size_t per_step = (size_t)BS * G4 * 4 + (size_t)BS * H * 2 + 1024;
    int C = (int)(rem / per_step);
    if (C < 1) C = 1;
    if (C > STEPS) C = STEPS;
    float*  xg  = (float*)take((size_t)BS * C * G4 * 4);
    __half* hck = (__half*)take((size_t)BS * C * H * 2);

    k_sort<<<1, 256, 0, stream>>>(lens, sidx, dlen, out_dec, out_sidx);
    k_gather<<<BS, 256, 0, stream>>>(caps, sidx, out_caps);
    k_wcomb<<<G4 * WV / 256, 256, 0, stream>>>(w_ih, W_emb, Wc);
    k_bcomb<<<G4 / 256, 256, 0, stream>>>(w_ih, b_ih, b_hh, b_emb, bc);
    k_packw8<<<4, 256, 0, stream>>>(w_hh, wq_l, wq_s, wscale);
    k_inithc<<<BS, 256, 0, stream>>>(enc, sidx, W_h, b_h, W_c, b_c, h_st, c_st);

    for (int t0 = 0; t0 < STEPS; t0 += C) {
        int Cc = STEPS - t0; if (Cc > C) Cc = C;
        dim3 g((Cc + 15) / 16, BS);
        k_xg<<<g, 256, 0, stream>>>(out_caps, Wc, bc, dlen, xg, t0, Cc);
        k_lstm<<<BS, 512, 0, stream>>>((const uint4*)wq_l, (const uint4*)wq_s, wscale,
                                       xg, dlen, h_st, c_st, hck, t0, Cc);
        k_logits<<<g, 256, 0, stream>>>(hck, W_out, b_out, dlen, out_pred, t0, Cc);
    }
}